// Round 2
// baseline (233.327 us; speedup 1.0000x reference)
//
#include <hip/hip_runtime.h>

// Walsh-Hadamard transform, N=4096 per row, fp32, scale 1/sqrt(4096)=1/64.
// H_4096 = H_16 (x) H_16 (x) H_16 -> three WHT16 passes over hex digits
// e = c*256 + b*16 + a. Pass order: c (strided loads), b, a (contiguous
// dwordx4 stores). Two padded-LDS transposes between passes.

constexpr int N = 4096;
constexpr int LDS_STRIDE = 17;   // 16+1 pad: all patterns <=2-way bank aliasing (free)

__device__ __forceinline__ void wht16(float v[16]) {
#pragma unroll
    for (int m = 1; m < 16; m <<= 1) {
#pragma unroll
        for (int g = 0; g < 16; g += 2 * m) {
#pragma unroll
            for (int k = 0; k < m; ++k) {
                float a = v[g + k];
                float b = v[g + k + m];
                v[g + k]     = a + b;
                v[g + k + m] = a - b;
            }
        }
    }
}

// 8 blocks/CU (32 waves = HW max): LDS 8*17408 = 139 KiB < 160 KiB, VGPR budget 64.
__global__ __launch_bounds__(256, 8) void fwht4096_kernel(const float* __restrict__ in,
                                                          float* __restrict__ out) {
    __shared__ float lds[256 * LDS_STRIDE];

    const int t = threadIdx.x;
    const size_t row = blockIdx.x;
    const float* __restrict__ src = in + row * (size_t)N;
    float* __restrict__ dst = out + row * (size_t)N;

    float v[16];

    // ---- pass 1 (digit c): thread t owns (b=t>>4, a=t&15); v[j] = x[j*256 + t]
    // 16 dword loads, each wave-instr reads 256 B contiguous; 16 outstanding -> MLP hides latency
#pragma unroll
    for (int j = 0; j < 16; ++j) v[j] = src[j * 256 + t];
    wht16(v);

    // ---- transpose 1: intermediate logical i = c*256 + a*16 + b, phys(i) = (i>>4)*17 + (i&15)
    // writer: i = j*256 + (t&15)*16 + (t>>4) -> phys = (j*16 + (t&15))*17 + (t>>4)
    {
        const int base = (t & 15) * LDS_STRIDE + (t >> 4);
#pragma unroll
        for (int j = 0; j < 16; ++j) lds[base + j * (16 * LDS_STRIDE)] = v[j];
    }
    __syncthreads();
    // reader: thread t wants all b for (c=t>>4, a=t&15): i = t*16 + b -> phys = t*17 + b
    {
        const int base = t * LDS_STRIDE;
#pragma unroll
        for (int p = 0; p < 16; ++p) v[p] = lds[base + p];
    }
    wht16(v);   // digit b done; thread t owns (c=t>>4, a=t&15), p = b
    __syncthreads();   // protect LDS before overwrite

    // ---- transpose 2: logical i2 = c*256 + b*16 + a
    // writer: i2 = (t>>4)*256 + p*16 + (t&15) -> phys = ((t>>4)*16 + p)*17 + (t&15)
    {
        const int base = (t >> 4) * (16 * LDS_STRIDE) + (t & 15);
#pragma unroll
        for (int p = 0; p < 16; ++p) lds[base + p * LDS_STRIDE] = v[p];
    }
    __syncthreads();
    // reader: thread t wants all a for (c=t>>4, b=t&15): i2 = t*16 + a -> phys = t*17 + a
    {
        const int base = t * LDS_STRIDE;
#pragma unroll
        for (int p = 0; p < 16; ++p) v[p] = lds[base + p];
    }
    wht16(v);   // digit a done; thread t holds e = t*16 + p, p=0..15 -> contiguous 64 B

    // ---- store: 4x dwordx4, wave writes 1 KiB contiguous per instruction
    const float scale = 0.015625f;  // 1/64 = 1/sqrt(4096)
    float4* d4 = (float4*)(dst + t * 16);
    d4[0] = make_float4(v[0] * scale,  v[1] * scale,  v[2] * scale,  v[3] * scale);
    d4[1] = make_float4(v[4] * scale,  v[5] * scale,  v[6] * scale,  v[7] * scale);
    d4[2] = make_float4(v[8] * scale,  v[9] * scale,  v[10] * scale, v[11] * scale);
    d4[3] = make_float4(v[12] * scale, v[13] * scale, v[14] * scale, v[15] * scale);
}

extern "C" void kernel_launch(void* const* d_in, const int* in_sizes, int n_in,
                              void* d_out, int out_size, void* d_ws, size_t ws_size,
                              hipStream_t stream) {
    const float* x = (const float*)d_in[0];
    float* y = (float*)d_out;
    const int rows = in_sizes[0] / N;   // 4*2048 = 8192
    fwht4096_kernel<<<rows, 256, 0, stream>>>(x, y);
}

// Round 3
// 227.771 us; speedup vs baseline: 1.0244x; 1.0244x over previous
//
#include <hip/hip_runtime.h>

// Walsh-Hadamard transform, N=4096/row, fp32, scale 1/64.
// H4096 = H16^3 over hex digits a(0-3), b(4-7), c(8-11); e = c*256+b*16+a.
// Pass order a,b,c: contiguous dwordx4 loads, two padded-LDS transposes,
// strided dword stores (stores are fire-and-forget; loads stay wide).
// 2 rows per block (independent LDS buffers) to halve barrier rate and
// double MLP -- round-2 showed we're latency/barrier-bound, not BW-bound.

constexpr int N = 4096;
constexpr int S = 17;   // LDS row stride (16+1): worst pattern ~2-3 way, ~0.5 cyc/instr measured

__device__ __forceinline__ void wht16(float v[16]) {
#pragma unroll
    for (int m = 1; m < 16; m <<= 1) {
#pragma unroll
        for (int g = 0; g < 16; g += 2 * m) {
#pragma unroll
            for (int k = 0; k < m; ++k) {
                float a = v[g + k];
                float b = v[g + k + m];
                v[g + k]     = a + b;
                v[g + k + m] = a - b;
            }
        }
    }
}

__device__ __forceinline__ void load16(float v[16], const float* __restrict__ p) {
    const float4* s4 = (const float4*)p;
    float4 f0 = s4[0], f1 = s4[1], f2 = s4[2], f3 = s4[3];
    v[0]=f0.x;  v[1]=f0.y;  v[2]=f0.z;  v[3]=f0.w;
    v[4]=f1.x;  v[5]=f1.y;  v[6]=f1.z;  v[7]=f1.w;
    v[8]=f2.x;  v[9]=f2.y;  v[10]=f2.z; v[11]=f2.w;
    v[12]=f3.x; v[13]=f3.y; v[14]=f3.z; v[15]=f3.w;
}

// T1: logical i = c*256 + a*16 + b, phys(i) = (i>>4)*S + (i&15)
__device__ __forceinline__ void t1_write(float* lds, const float v[16], int t) {
    const int base = (t >> 4) * (16 * S) + (t & 15);
#pragma unroll
    for (int j = 0; j < 16; ++j) lds[base + j * S] = v[j];
}
// T2: logical i2 = b*256 + a*16 + c
__device__ __forceinline__ void t2_write(float* lds, const float v[16], int t) {
    const int base = (t & 15) * S + (t >> 4);
#pragma unroll
    for (int p = 0; p < 16; ++p) lds[base + p * (16 * S)] = v[p];
}
__device__ __forceinline__ void rd16(const float* lds, float v[16], int t) {
    const int base = t * S;
#pragma unroll
    for (int p = 0; p < 16; ++p) v[p] = lds[base + p];
}

// LDS 2*17408 = 34816 B/block -> 4 blocks/CU (16 waves); VGPR budget 128.
__global__ __launch_bounds__(256, 4) void fwht4096_kernel(const float* __restrict__ in,
                                                          float* __restrict__ out) {
    __shared__ float lds0[256 * S];
    __shared__ float lds1[256 * S];

    const int t = threadIdx.x;
    const size_t row0 = (size_t)blockIdx.x * 2;
    const float* __restrict__ s0 = in + row0 * (size_t)N;
    const float* __restrict__ s1 = s0 + N;
    float* __restrict__ d0 = out + row0 * (size_t)N;
    float* __restrict__ d1 = d0 + N;

    float v0[16], v1[16];

    // 8 dwordx4 loads in flight, then two independent WHT chains
    load16(v0, s0 + t * 16);
    load16(v1, s1 + t * 16);
    wht16(v0);  wht16(v1);                 // digit a

    t1_write(lds0, v0, t);
    t1_write(lds1, v1, t);
    __syncthreads();
    rd16(lds0, v0, t);                     // owns (c=t>>4, a=t&15), p=b
    rd16(lds1, v1, t);
    wht16(v0);  wht16(v1);                 // digit b
    __syncthreads();                       // protect buffers before overwrite

    t2_write(lds0, v0, t);
    t2_write(lds1, v1, t);
    __syncthreads();
    rd16(lds0, v0, t);                     // owns (b=t>>4, a=t&15), p=c
    rd16(lds1, v1, t);
    wht16(v0);  wht16(v1);                 // digit c

    // e = p*256 + (t>>4)*16 + (t&15) = p*256 + t ; 256 B per wave-instr, fire-and-forget
    const float scale = 0.015625f;         // 1/sqrt(4096)
#pragma unroll
    for (int p = 0; p < 16; ++p) {
        d0[p * 256 + t] = v0[p] * scale;
        d1[p * 256 + t] = v1[p] * scale;
    }
}

extern "C" void kernel_launch(void* const* d_in, const int* in_sizes, int n_in,
                              void* d_out, int out_size, void* d_ws, size_t ws_size,
                              hipStream_t stream) {
    const float* x = (const float*)d_in[0];
    float* y = (float*)d_out;
    const int rows = in_sizes[0] / N;        // 8192
    fwht4096_kernel<<<rows / 2, 256, 0, stream>>>(x, y);
}